// Round 4
// baseline (16672.867 us; speedup 1.0000x reference)
//
#include <hip/hip_runtime.h>

// LDS layout (dynamic, 144 KB)
#define LWT  0            // 8 weight tiles x 16 KB (pre-swizzled B-frags, K=512)
#define LWE  131072       // emb_W tile (K=256), 8 KB
#define LRB  139264       // r-gate buf f32[1024]
#define LZB  143360       // z-gate buf f32[1024]
#define LDS_TOTAL 147456

typedef short bf16x8 __attribute__((ext_vector_type(8)));
typedef float f32x4 __attribute__((ext_vector_type(4)));

static __device__ __forceinline__ unsigned short f2b(float x){
  union { float f; unsigned u; } v; v.f = x;
  unsigned r = v.u + 0x7fffu + ((v.u >> 16) & 1u);
  return (unsigned short)(r >> 16);
}
static __device__ __forceinline__ float sigmoidf_(float x){
  return 1.0f / (1.0f + __expf(-x));
}
static __device__ __forceinline__ float tanhf_(float x){
  float e2 = __expf(-2.0f * fabsf(x));
  float t = (1.0f - e2) / (1.0f + e2);
  return x < 0.0f ? -t : t;
}
static __device__ __forceinline__ bf16x8 pack8(f32x4 u0, f32x4 u1){
  bf16x8 a;
  a[0] = (short)f2b(u0[0]); a[1] = (short)f2b(u0[1]);
  a[2] = (short)f2b(u0[2]); a[3] = (short)f2b(u0[3]);
  a[4] = (short)f2b(u1[0]); a[5] = (short)f2b(u1[1]);
  a[6] = (short)f2b(u1[2]); a[7] = (short)f2b(u1[3]);
  return a;
}

// per-group barrier: 32 blocks, gen-counter, agent scope
static __device__ __forceinline__ void gbar(unsigned* cnt, unsigned* gen){
  __syncthreads();
  __threadfence();
  if (threadIdx.x == 0){
    unsigned g = __hip_atomic_load(gen, __ATOMIC_RELAXED, __HIP_MEMORY_SCOPE_AGENT);
    unsigned a = __hip_atomic_fetch_add(cnt, 1u, __ATOMIC_ACQ_REL, __HIP_MEMORY_SCOPE_AGENT);
    if (a == 31u){
      __hip_atomic_store(cnt, 0u, __ATOMIC_RELAXED, __HIP_MEMORY_SCOPE_AGENT);
      __hip_atomic_fetch_add(gen, 1u, __ATOMIC_RELEASE, __HIP_MEMORY_SCOPE_AGENT);
    } else {
      while (__hip_atomic_load(gen, __ATOMIC_ACQUIRE, __HIP_MEMORY_SCOPE_AGENT) == g)
        __builtin_amdgcn_s_sleep(1);
    }
  }
  __syncthreads();     // everyone waits for thread0's wake
  __threadfence();     // acquire: invalidate caches AFTER data is globally visible
}

static __device__ __forceinline__ void loadAfr(bf16x8* Af, const unsigned short* base,
                                               int m, int ln, int kq){
  const unsigned short* p = base + (size_t)(m * 16 + ln) * 512 + kq * 8;
  #pragma unroll
  for (int k = 0; k < 16; k++) Af[k] = *(const bf16x8*)(p + k * 32);
}
static __device__ __forceinline__ void mm16(f32x4& acc, const bf16x8* Af, const bf16x8* Bf){
  #pragma unroll
  for (int k = 0; k < 16; k++)
    acc = __builtin_amdgcn_mfma_f32_16x16x32_bf16(Af[k], Bf[k], acc, 0, 0, 0);
}

// ---------------- prologue: vectorized casts + transposes + fused biases ----------------
__global__ __launch_bounds__(256)
void k_prep(const float* __restrict__ embW, const float* __restrict__ emb_b,
            const float* __restrict__ w_ih, const float* __restrict__ w_hh,
            const float* __restrict__ b_hh,
            const float* __restrict__ out_W, const float* __restrict__ out_b,
            const float* __restrict__ reg_W, const float* __restrict__ reg_b,
            unsigned short* __restrict__ wih16, unsigned short* __restrict__ Wbig,
            unsigned short* __restrict__ embW16, unsigned short* __restrict__ regW16,
            unsigned short* __restrict__ outWT16, float* __restrict__ bias_big,
            unsigned* __restrict__ bar)
{
  int b = blockIdx.x, t = threadIdx.x;
  auto cast8 = [&](const float* s, unsigned short* d, int i8){
    f32x4 u0 = *(const f32x4*)(s + i8);
    f32x4 u1 = *(const f32x4*)(s + i8 + 4);
    *(bf16x8*)(d + i8) = pack8(u0, u1);
  };
  if (b < 384){ cast8(w_ih, wih16, b * 2048 + t * 8); }
  else if (b < 768){ cast8(w_hh, Wbig + (size_t)512 * 512, (b - 384) * 2048 + t * 8); }
  else if (b < 832){ cast8(embW, embW16, (b - 768) * 2048 + t * 8); }
  else if (b < 840){ cast8(reg_W, regW16, (b - 832) * 2048 + t * 8); }
  else if (b < 904){
    int i8 = (b - 840) * 2048 + t * 8;
    int j = i8 >> 8, k0 = i8 & 255;
    bf16x8 v;
    #pragma unroll
    for (int u = 0; u < 8; u++) v[u] = (short)f2b(out_W[(size_t)(k0 + u) * 512 + j]);
    *(bf16x8*)(outWT16 + i8) = v;
  }
  else if (b < 913){
    int i = (b - 904) * 256 + t;
    if (i < 512){
      float s = emb_b[i];
      for (int k = 0; k < 256; k++) s += embW[i * 256 + k] * out_b[k];
      bias_big[i] = s;
    } else if (i < 2048){
      bias_big[i] = b_hh[i - 512];
    } else if (i < 2112){
      int o = i - 2048;
      float s = reg_b[o];
      for (int k = 0; k < 256; k++) s += reg_W[o * 256 + k] * out_b[k];
      bias_big[i] = s;
    }
  }
  else { bar[t] = 0u; bar[t + 256] = 0u; }
}

// ---------------- weight-fold GEMMs: Wc = embW @ outW^T fold, W_or = regW @ outW^T ----------------
static __device__ void fold_tile(const float* __restrict__ A,
                                 const unsigned short* __restrict__ W,
                                 unsigned short* __restrict__ C,
                                 int K, int ldc, int bx, int by)
{
  const int lane = threadIdx.x & 63;
  const int wave = threadIdx.x >> 6;
  const int ln = lane & 15;
  const int kq = lane >> 4;
  const int m0 = by * 64 + wave * 16;
  const int n0 = bx * 64;
  f32x4 acc[4] = {};
  const float* ap = A + (size_t)(m0 + ln) * K + kq * 8;
  const unsigned short* wp = W + (size_t)(n0 + ln) * K + kq * 8;
  for (int t = 0; t < (K >> 5); ++t){
    f32x4 u0 = *(const f32x4*)(ap);
    f32x4 u1 = *(const f32x4*)(ap + 4);
    bf16x8 af = pack8(u0, u1);
    #pragma unroll
    for (int j = 0; j < 4; j++){
      bf16x8 wf = *(const bf16x8*)(wp + (size_t)(16 * j) * K);
      acc[j] = __builtin_amdgcn_mfma_f32_16x16x32_bf16(af, wf, acc[j], 0, 0, 0);
    }
    ap += 32; wp += 32;
  }
  #pragma unroll
  for (int j = 0; j < 4; j++){
    int col = n0 + 16 * j + ln;
    #pragma unroll
    for (int r = 0; r < 4; r++)
      C[(size_t)(m0 + kq * 4 + r) * ldc + col] = f2b(acc[j][r]);
  }
}

__global__ __launch_bounds__(256)
void k_gemms(const float* __restrict__ embW, const float* __restrict__ reg_W,
             const unsigned short* __restrict__ outWT16,
             unsigned short* __restrict__ Wbig)
{
  int b = blockIdx.x;
  if (b < 64) fold_tile(embW, outWT16, Wbig, 256, 512, b & 7, b >> 3);
  else        fold_tile(reg_W, outWT16, Wbig + (size_t)2048 * 512, 256, 512, b - 64, 0);
}

// ---------------- main: LDS-resident weight slices + per-group barrier ----------------
__global__ __launch_bounds__(256, 1)
void k_loop(const float* __restrict__ enc, const float* __restrict__ ehid,
            const float* __restrict__ emb_b, const float* __restrict__ b_ih,
            const float* __restrict__ b_hh,
            const unsigned short* __restrict__ wih16,
            const unsigned short* __restrict__ Wbig,
            const unsigned short* __restrict__ embW16,
            const unsigned short* __restrict__ regW16,
            const float* __restrict__ bias_big, const float* __restrict__ reg_b,
            unsigned short* h16g, unsigned short* e16g,
            unsigned* bar, float* __restrict__ out)
{
  extern __shared__ char sm[];
  char* ldsWT = sm;
  float* rbuf = (float*)(sm + LRB);
  float* zbuf = (float*)(sm + LZB);

  const int blk = blockIdx.x;
  const int tid = threadIdx.x;
  const int w = tid >> 6;
  const int lane = tid & 63;
  const int ln = lane & 15;
  const int kq = lane >> 4;
  const int g = blk >> 5;       // group 0..7 (64 batch rows)
  const int c = blk & 31;       // column-slice 0..31 (16 GRU units)
  const int j0 = c * 16;
  const int j = j0 + ln;

  unsigned short* Hg = h16g + (size_t)g * 64 * 512;
  unsigned short* Eg = e16g + (size_t)g * 64 * 512;
  unsigned* cnt = bar + g * 64;
  unsigned* gen = bar + g * 64 + 16;

  // ---- encoder projection (pre-phase, all blocks) ----
  for (int t = blk; t < 1120; t += 256){
    const int m0r = t * 64 + w * 16;
    f32x4 acc4[4] = {};
    const float* ap = enc + (size_t)(m0r + ln) * 256 + kq * 8;
    bf16x8 Afr[8];
    #pragma unroll
    for (int k = 0; k < 8; k++){
      f32x4 u0 = *(const f32x4*)(ap + k * 32);
      f32x4 u1 = *(const f32x4*)(ap + k * 32 + 4);
      Afr[k] = pack8(u0, u1);
    }
    #pragma unroll
    for (int c4 = 0; c4 < 4; c4++){
      const unsigned short* bp = regW16 + (size_t)(c4 * 16 + ln) * 256 + kq * 8;
      #pragma unroll
      for (int k = 0; k < 8; k++){
        bf16x8 wf = *(const bf16x8*)(bp + k * 32);
        acc4[c4] = __builtin_amdgcn_mfma_f32_16x16x32_bf16(Afr[k], wf, acc4[c4], 0, 0, 0);
      }
    }
    #pragma unroll
    for (int c4 = 0; c4 < 4; c4++){
      float bv = reg_b[c4 * 16 + ln];
      #pragma unroll
      for (int r = 0; r < 4; r++){
        int orow = m0r + kq * 4 + r;
        int bb = orow / 140, tt = orow - bb * 140;
        out[((size_t)bb * 280 + tt) * 64 + c4 * 16 + ln] = acc4[c4][r] + bv;
      }
    }
  }

  // ---- stage weight slices into LDS, pre-swizzled into B-frag order ----
  auto stage512 = [&](int tile, const unsigned short* src){
    for (int slot = tid; slot < 1024; slot += 256){
      int l6 = slot & 63, k = slot >> 6;
      const unsigned short* p = src + (size_t)(l6 & 15) * 512 + k * 32 + (l6 >> 4) * 8;
      *(bf16x8*)(ldsWT + (size_t)tile * 16384 + (size_t)slot * 16) = *(const bf16x8*)p;
    }
  };
  stage512(0, wih16 + (size_t)j0 * 512);            // gi R
  stage512(1, wih16 + (size_t)(512  + j0) * 512);   // gi Z
  stage512(2, wih16 + (size_t)(1024 + j0) * 512);   // gi N
  stage512(3, Wbig  + (size_t)(512  + j0) * 512);   // gh R
  stage512(4, Wbig  + (size_t)(1024 + j0) * 512);   // gh Z
  stage512(5, Wbig  + (size_t)(1536 + j0) * 512);   // gh N
  stage512(6, Wbig  + (size_t)j0 * 512);            // Wc (e)
  if (c < 4) stage512(7, Wbig + (size_t)(2048 + c * 16) * 512);  // W_or slice
  for (int slot = tid; slot < 512; slot += 256){     // emb_W tile (K=256)
    int l6 = slot & 63, k = slot >> 6;
    const unsigned short* p = embW16 + (size_t)(j0 + (l6 & 15)) * 256 + k * 32 + (l6 >> 4) * 8;
    *(bf16x8*)(ldsWT + LWE + (size_t)slot * 16) = *(const bf16x8*)p;
  }

  // ---- init h16 slice + persistent h registers (wave2) ----
  for (int i = tid; i < 1024; i += 256){
    int rr = i >> 4, cc = i & 15;
    Hg[(size_t)rr * 512 + j0 + cc] = f2b(ehid[(size_t)(g * 64 + rr) * 512 + j0 + cc]);
  }
  float hreg[4][4];
  if (w == 2){
    #pragma unroll
    for (int m = 0; m < 4; m++)
      #pragma unroll
      for (int r = 0; r < 4; r++)
        hreg[m][r] = ehid[(size_t)(g * 64 + m * 16 + kq * 4 + r) * 512 + j];
  }

  // per-wave biases
  float bRZ = 0.f, bIN = 0.f, bHN = 0.f, bE = 0.f, bE0 = 0.f, bY = 0.f;
  if (w == 0) bRZ = b_ih[j] + b_hh[j];
  if (w == 1) bRZ = b_ih[512 + j] + b_hh[512 + j];
  if (w == 2){ bIN = b_ih[1024 + j]; bHN = b_hh[1024 + j]; }
  if (w == 3){ bE = bias_big[j]; bE0 = emb_b[j]; }
  if (c < 4) bY = bias_big[2048 + c * 16 + ln];

  f32x4 ghacc[4];   // carried P1 -> P2 (waves 0-2)

  // ---- P1 phase: gh (waves 0-2), e (wave3), y (fused, all waves, c<4) ----
  auto p1phase = [&](bool p10, int s){
    const bool yact = (c < 4) && !p10;
    f32x4 yacc = {};
    if (w < 3){
      bf16x8 Bf[16];
      #pragma unroll
      for (int k = 0; k < 16; k++)
        Bf[k] = *(const bf16x8*)(ldsWT + (size_t)(3 + w) * 16384 + ((size_t)k * 64 + lane) * 16);
      #pragma unroll
      for (int m = 0; m < 4; m++) ghacc[m] = (f32x4){};
      bf16x8 Aa[16], Ab[16];
      loadAfr(Aa, Hg, 0, ln, kq);
      #pragma unroll
      for (int m = 0; m < 4; m++){
        const bf16x8* cur = (m & 1) ? Ab : Aa;
        if (m < 3) loadAfr((m & 1) ? Aa : Ab, Hg, m + 1, ln, kq);
        mm16(ghacc[m], cur, Bf);
        if (yact && m == w){
          #pragma unroll
          for (int k = 0; k < 16; k++){
            bf16x8 By = *(const bf16x8*)(ldsWT + (size_t)7 * 16384 + ((size_t)k * 64 + lane) * 16);
            yacc = __builtin_amdgcn_mfma_f32_16x16x32_bf16(cur[k], By, yacc, 0, 0, 0);
          }
        }
      }
    } else {
      f32x4 eacc[4] = {};
      if (!p10){
        bf16x8 Bf[16];
        #pragma unroll
        for (int k = 0; k < 16; k++)
          Bf[k] = *(const bf16x8*)(ldsWT + (size_t)6 * 16384 + ((size_t)k * 64 + lane) * 16);
        bf16x8 Aa[16], Ab[16];
        loadAfr(Aa, Hg, 0, ln, kq);
        #pragma unroll
        for (int m = 0; m < 4; m++){
          const bf16x8* cur = (m & 1) ? Ab : Aa;
          if (m < 3) loadAfr((m & 1) ? Aa : Ab, Hg, m + 1, ln, kq);
          mm16(eacc[m], cur, Bf);
          if (yact && m == 3){
            #pragma unroll
            for (int k = 0; k < 16; k++){
              bf16x8 By = *(const bf16x8*)(ldsWT + (size_t)7 * 16384 + ((size_t)k * 64 + lane) * 16);
              yacc = __builtin_amdgcn_mfma_f32_16x16x32_bf16(cur[k], By, yacc, 0, 0, 0);
            }
          }
        }
      } else {
        bf16x8 BfE[8];
        #pragma unroll
        for (int k = 0; k < 8; k++)
          BfE[k] = *(const bf16x8*)(ldsWT + LWE + ((size_t)k * 64 + lane) * 16);
        #pragma unroll
        for (int m = 0; m < 4; m++){
          const float* xp = enc + ((size_t)(g * 64 + m * 16 + ln) * 140 + 139) * 256 + kq * 8;
          bf16x8 Af[8];
          #pragma unroll
          for (int k = 0; k < 8; k++){
            f32x4 u0 = *(const f32x4*)(xp + k * 32);
            f32x4 u1 = *(const f32x4*)(xp + k * 32 + 4);
            Af[k] = pack8(u0, u1);
          }
          #pragma unroll
          for (int k = 0; k < 8; k++)
            eacc[m] = __builtin_amdgcn_mfma_f32_16x16x32_bf16(Af[k], BfE[k], eacc[m], 0, 0, 0);
        }
      }
      float be = p10 ? bE0 : bE;
      #pragma unroll
      for (int m = 0; m < 4; m++)
        #pragma unroll
        for (int r = 0; r < 4; r++){
          float v = eacc[m][r] + be;
          Eg[(size_t)(m * 16 + kq * 4 + r) * 512 + j] = f2b(v > 0.f ? v : 0.f);
        }
    }
    if (yact){
      #pragma unroll
      for (int r = 0; r < 4; r++){
        int b = g * 64 + w * 16 + kq * 4 + r;
        out[((size_t)b * 280 + 140 + s) * 64 + c * 16 + ln] = yacc[r] + bY;
      }
    }
  };

  // ---- P2 phase: gi (waves 0-2), gates + h update (wave2) ----
  auto p2phase = [&](){
    f32x4 acc[4];
    if (w < 3){
      bf16x8 Bf[16];
      #pragma unroll
      for (int k = 0; k < 16; k++)
        Bf[k] = *(const bf16x8*)(ldsWT + (size_t)w * 16384 + ((size_t)k * 64 + lane) * 16);
      #pragma unroll
      for (int m = 0; m < 4; m++) acc[m] = (w == 2) ? (f32x4){} : ghacc[m];
      bf16x8 Aa[16], Ab[16];
      loadAfr(Aa, Eg, 0, ln, kq);
      #pragma unroll
      for (int m = 0; m < 4; m++){
        const bf16x8* cur = (m & 1) ? Ab : Aa;
        if (m < 3) loadAfr((m & 1) ? Aa : Ab, Eg, m + 1, ln, kq);
        mm16(acc[m], cur, Bf);
      }
      if (w == 0){
        #pragma unroll
        for (int m = 0; m < 4; m++)
          #pragma unroll
          for (int r = 0; r < 4; r++)
            rbuf[m * 256 + (kq * 4 + r) * 16 + ln] = sigmoidf_(acc[m][r] + bRZ);
      } else if (w == 1){
        #pragma unroll
        for (int m = 0; m < 4; m++)
          #pragma unroll
          for (int r = 0; r < 4; r++)
            zbuf[m * 256 + (kq * 4 + r) * 16 + ln] = sigmoidf_(acc[m][r] + bRZ);
      }
    }
    __syncthreads();
    if (w == 2){
      #pragma unroll
      for (int m = 0; m < 4; m++)
        #pragma unroll
        for (int r = 0; r < 4; r++){
          int idx = m * 256 + (kq * 4 + r) * 16 + ln;
          float rv = rbuf[idx], zv = zbuf[idx];
          float nv = tanhf_(acc[m][r] + bIN + rv * (ghacc[m][r] + bHN));
          float hv = (1.f - zv) * nv + zv * hreg[m][r];
          hreg[m][r] = hv;
          Hg[(size_t)(m * 16 + kq * 4 + r) * 512 + j] = f2b(hv);
        }
    }
  };

  gbar(cnt, gen);        // init h16/e-staging visible; LDS staged
  p1phase(true, 0);      // gh0 + e0 (from x0)
  gbar(cnt, gen);
  for (int s = 0; s < 140; ++s){
    p2phase();
    gbar(cnt, gen);
    p1phase(false, s);
    if (s != 139) gbar(cnt, gen);
  }
}

extern "C" void kernel_launch(void* const* d_in, const int* in_sizes, int n_in,
                              void* d_out, int out_size, void* d_ws, size_t ws_size,
                              hipStream_t stream)
{
  const float* enc   = (const float*)d_in[0];
  const float* ehid  = (const float*)d_in[1];
  const float* embW  = (const float*)d_in[2];
  const float* emb_b = (const float*)d_in[3];
  const float* w_ih  = (const float*)d_in[4];
  const float* w_hh  = (const float*)d_in[5];
  const float* b_ih  = (const float*)d_in[6];
  const float* b_hh  = (const float*)d_in[7];
  const float* out_W = (const float*)d_in[8];
  const float* out_b = (const float*)d_in[9];
  const float* reg_W = (const float*)d_in[10];
  const float* reg_b = (const float*)d_in[11];
  float* out = (float*)d_out;

  char* ws = (char*)d_ws;
  size_t off = 0;
  auto alloc = [&](size_t bytes)->char*{
    char* p = ws + off; off += (bytes + 255) & ~(size_t)255; return p;
  };
  unsigned short* Wbig    = (unsigned short*)alloc((size_t)2112 * 512 * 2);
  unsigned short* wih16   = (unsigned short*)alloc((size_t)1536 * 512 * 2);
  unsigned short* embW16  = (unsigned short*)alloc((size_t)512 * 256 * 2);
  unsigned short* regW16  = (unsigned short*)alloc((size_t)64 * 256 * 2);
  unsigned short* outWT16 = (unsigned short*)alloc((size_t)512 * 256 * 2);
  float*          bias_big= (float*)alloc((size_t)2112 * 4);
  unsigned short* h16g    = (unsigned short*)alloc((size_t)512 * 512 * 2);
  unsigned short* e16g    = (unsigned short*)alloc((size_t)512 * 512 * 2);
  unsigned*       bar     = (unsigned*)alloc(2048);

  static int attr_set = 0;
  (void)hipFuncSetAttribute((const void*)k_loop,
                            hipFuncAttributeMaxDynamicSharedMemorySize, LDS_TOTAL);
  (void)attr_set;

  k_prep<<<914, 256, 0, stream>>>(embW, emb_b, w_ih, w_hh, b_hh,
                                  out_W, out_b, reg_W, reg_b,
                                  wih16, Wbig, embW16, regW16, outWT16, bias_big, bar);

  k_gemms<<<72, 256, 0, stream>>>(embW, reg_W, outWT16, Wbig);

  k_loop<<<256, 256, LDS_TOTAL, stream>>>(enc, ehid, emb_b, b_ih, b_hh,
                                          wih16, Wbig, embW16, regW16,
                                          bias_big, reg_b, h16g, e16g, bar, out);
}